// Round 1
// baseline (174.928 us; speedup 1.0000x reference)
//
#include <hip/hip_runtime.h>

// LoRA linear, fp32 in/out: out = x @ (W + 2*B@A)^T + b
//   prep:   [0..511] Weff = bf16(W + 2*B@A) (2 MiB); [512..] xbf = bf16(x) (32 MiB)
//   gemm256: 256x256x64 8-phase-schedule bf16 MFMA GEMM (HK/m201 template, plain HIP):
//            counted vmcnt(6) (never drain-0 in loop), raw s_barrier, XOR k-chunk
//            swizzle (2-way max), setprio around MFMA clusters, XCD-chunked blockIdx.
//   Fallback (ws too small): old 128x128 kernel, A staged via fp32 loads + HW cvt.

typedef __bf16 bf16x8 __attribute__((ext_vector_type(8)));
typedef float f32x4 __attribute__((ext_vector_type(4)));
typedef unsigned short ushort8 __attribute__((ext_vector_type(8)));

__device__ __forceinline__ unsigned short f2bf(float f) {
    __bf16 h = (__bf16)f;                       // HW RNE convert
    union { __bf16 b; unsigned short u; } v; v.b = h; return v.u;
}
__device__ __forceinline__ ushort8 cvt8(f32x4 a, f32x4 b) {
    ushort8 o;
#pragma unroll
    for (int i = 0; i < 4; ++i) { o[i] = f2bf(a[i]); o[i + 4] = f2bf(b[i]); }
    return o;
}
__device__ __forceinline__ void gld16(const unsigned short* g, unsigned short* l) {
    __builtin_amdgcn_global_load_lds(
        (const __attribute__((address_space(1))) unsigned int*)g,
        (__attribute__((address_space(3))) unsigned int*)l, 16, 0, 0);
}

#define FENCE() asm volatile("" ::: "memory")
#define BARRIER() do { FENCE(); __builtin_amdgcn_s_barrier(); FENCE(); } while (0)

// ---------------- prep: Weff fold + x conversion (unchanged) ----------------
__global__ __launch_bounds__(256) void prep(
    const float* __restrict__ X, const float* __restrict__ W,
    const float* __restrict__ A, const float* __restrict__ B,
    unsigned short* __restrict__ xbf, unsigned short* __restrict__ Weff)
{
    const int b = blockIdx.x;
    if (b < 512) {
        const int idx = b * 256 + threadIdx.x;
        const int o  = idx >> 7;
        const int kc = (idx & 127) << 3;
        float br[16];
#pragma unroll
        for (int r = 0; r < 16; ++r) br[r] = 2.0f * B[o * 16 + r];
        float acc[8];
        const float* wrow = W + (size_t)o * 1024 + kc;
#pragma unroll
        for (int j = 0; j < 8; ++j) acc[j] = wrow[j];
#pragma unroll
        for (int r = 0; r < 16; ++r) {
            const float* arow = A + r * 1024 + kc;
#pragma unroll
            for (int j = 0; j < 8; ++j) acc[j] += br[r] * arow[j];
        }
        ushort8 o8;
#pragma unroll
        for (int j = 0; j < 8; ++j) o8[j] = f2bf(acc[j]);
        *(ushort8*)(Weff + (size_t)o * 1024 + kc) = o8;
    } else {
        const size_t i = ((size_t)(b - 512) * 256 + threadIdx.x) * 8;
        f32x4 a = *(const f32x4*)(X + i);
        f32x4 c = *(const f32x4*)(X + i + 4);
        *(ushort8*)(xbf + i) = cvt8(a, c);
    }
}

// ---------------- gemm256: 8-phase 256x256 schedule ----------------
// Geometry: BM=BN=256, BK=64, 512 thr = 8 waves (2M x 4N), per-wave C = 128x64
//   (8 M-frags x 4 N-frags of 16x16, acc[8][4] f32x4 = 128 VGPR).
// LDS 128 KiB: 2 bufs x { A[2 halves][128][64] ; B[2 halves][128][64] } bf16.
//   half-tile = 128x64 = 16 KiB = 512 thr x 2 gld16. Region offsets (ushorts):
//   buf*32768 + {A0:0, A1:8192, B0:16384, B1:24576}.
// Swizzle: 16B-chunk index (0..7 within a 128 B row) XOR (row&7). Reads (rows
//   vary per lane at fixed chunk) become <=2-way; global source pre-swizzled,
//   LDS dest linear (global_load_lds constraint, guide rule #21).
// Stage slots (tile j, phases p0..p3): p0 -> B1 of tile j+1 (into buf j+1);
//   p1/p2/p3 -> A0/A1/B0 of tile j+2 (into buf j = cur; its ds_reads fully
//   drain at p0/p1, so cur is writable from p1 on). Checkpoint at p3:
//   vmcnt(6) leaves only {A0,A1,B0 of j+2} (slots p1..p3) in flight =>
//   everything tile j+1 needs is landed before its p0. Last-tile peeling:
//   j=14 uses vmcnt(0), j>=14 stages nothing beyond tile 15.
template<int MH, int NH>
__device__ __forceinline__ void qmfma(f32x4 (&acc)[8][4],
                                      const bf16x8 (&fa)[8][2],
                                      const bf16x8 (&fb)[4][2]) {
#pragma unroll
    for (int m2 = 0; m2 < 4; ++m2)
#pragma unroll
        for (int n2 = 0; n2 < 2; ++n2)
#pragma unroll
            for (int ks = 0; ks < 2; ++ks)
                acc[MH * 4 + m2][NH * 2 + n2] = __builtin_amdgcn_mfma_f32_16x16x32_bf16(
                    fa[MH * 4 + m2][ks], fb[NH * 2 + n2][ks],
                    acc[MH * 4 + m2][NH * 2 + n2], 0, 0, 0);
}

#define PHASE_MFMA(MH, NH)                                          \
    do { BARRIER();                                                 \
         asm volatile("s_waitcnt lgkmcnt(0)" ::: "memory");         \
         __builtin_amdgcn_sched_barrier(0); /* rule 18 */           \
         __builtin_amdgcn_s_setprio(1);                             \
         qmfma<MH, NH>(acc, fa, fb);                                \
         __builtin_amdgcn_s_setprio(0);                             \
         BARRIER(); } while (0)

__global__ __launch_bounds__(512, 2) void gemm256(
    const unsigned short* __restrict__ Xb,     // bf16 [M][1024]
    const unsigned short* __restrict__ Wt,     // bf16 Weff [1024][1024]
    const float* __restrict__ bias,            // fp32 [1024]
    float* __restrict__ out)                   // fp32 [M][1024]
{
    extern __shared__ __align__(16) unsigned short lds[];   // 131072 B

    const int t    = threadIdx.x;
    const int lane = t & 63;
    const int w    = t >> 6;
    const int wr   = w >> 2;        // 0..1 (M)
    const int wc   = w & 3;         // 0..3 (N)
    const int r16  = lane & 15;
    const int quad = lane >> 4;

    // XCD-chunked block swizzle (nwg=256 % 8 == 0 -> bijective). N/BN=4 fixed.
    const int nwg = gridDim.x;
    int swz = blockIdx.x;
    if ((nwg & 7) == 0) swz = (swz & 7) * (nwg >> 3) + (swz >> 3);
    const int bm = (swz >> 2) * 256;
    const int bn = (swz & 3) * 256;

    // ---- staging constants: thread t owns chunks c0,c1 of each half-tile ----
    const int c0 = w * 128 + lane, c1 = c0 + 64;       // chunk ids (16 B each)
    const int r0 = c0 >> 3,        r1 = c1 >> 3;       // half-local rows 0..127
    const int s0c = (c0 & 7) ^ (r0 & 7);               // pre-swizzled src chunk
    const int s1c = (c1 & 7) ^ (r1 & 7);
    const unsigned short* pA0 = Xb + (size_t)(bm + r0) * 1024 + s0c * 8;
    const unsigned short* pA1 = Xb + (size_t)(bm + r1) * 1024 + s1c * 8;
    const unsigned short* pB0 = Wt + (size_t)(bn + r0) * 1024 + s0c * 8;
    const unsigned short* pB1 = Wt + (size_t)(bn + r1) * 1024 + s1c * 8;
    const int lc0 = c0 * 8, lc1 = c1 * 8;              // linear LDS dest (ushorts)

    // ---- reader constants: frag addr = buf + base + mt*1024, ^32 toggles ks ----
    const int ck    = (quad ^ (r16 & 7)) * 8;                          // swz chunk
    const int aBase = wr * 8192 + r16 * 64 + ck;                       // A half wr
    const int bBase = 16384 + (wc >> 1) * 8192 + (wc & 1) * 4096 + r16 * 64 + ck;

    f32x4 acc[8][4];
#pragma unroll
    for (int i = 0; i < 8; ++i)
#pragma unroll
        for (int jj = 0; jj < 4; ++jj)
            acc[i][jj] = (f32x4){0.f, 0.f, 0.f, 0.f};

    // ---- prologue: tile0 -> buf0 (4 halves), tile1 -> buf1 (A0,A1,B0) ----
    // FENCE between groups pins issue order so vmcnt(6) counts correctly.
    gld16(pA0,               lds + lc0);            gld16(pA1,               lds + lc1);            FENCE();
    gld16(pA0 + 131072,      lds + 8192  + lc0);    gld16(pA1 + 131072,      lds + 8192  + lc1);    FENCE();
    gld16(pB0,               lds + 16384 + lc0);    gld16(pB1,               lds + 16384 + lc1);    FENCE();
    gld16(pB0 + 131072,      lds + 24576 + lc0);    gld16(pB1 + 131072,      lds + 24576 + lc1);    FENCE();
    gld16(pA0 + 64,          lds + 32768 + lc0);    gld16(pA1 + 64,          lds + 32768 + lc1);    FENCE();
    gld16(pA0 + 131072 + 64, lds + 40960 + lc0);    gld16(pA1 + 131072 + 64, lds + 40960 + lc1);    FENCE();
    gld16(pB0 + 64,          lds + 49152 + lc0);    gld16(pB1 + 64,          lds + 49152 + lc1);
    asm volatile("s_waitcnt vmcnt(6)" ::: "memory");   // tile0 fully landed
    BARRIER();

#pragma unroll 2
    for (int j = 0; j < 16; ++j) {
        const unsigned short* Lb = lds + (j & 1) * 32768;        // compute buf
        unsigned short* Sc = lds + (j & 1) * 32768;              // stage p1..p3
        unsigned short* Sn = lds + ((j & 1) ^ 1) * 32768;        // stage p0
        const int k1 = (j + 1) * 64, k2 = (j + 2) * 64;

        bf16x8 fa[8][2], fb[4][2];

        // ---------- phase 0: quadrant (0,0) ----------
        // reads: fa[0..3]+fb[0..1] (all waves); fa[4..7] for wr==0 (A0 region
        // is overwritten at p1, so wr0 must read everything now).
#pragma unroll
        for (int mt = 0; mt < 4; ++mt) {
            fa[mt][0] = *(const bf16x8*)(Lb + aBase + mt * 1024);
            fa[mt][1] = *(const bf16x8*)(Lb + (aBase ^ 32) + mt * 1024);
        }
#pragma unroll
        for (int nt = 0; nt < 2; ++nt) {
            fb[nt][0] = *(const bf16x8*)(Lb + bBase + nt * 1024);
            fb[nt][1] = *(const bf16x8*)(Lb + (bBase ^ 32) + nt * 1024);
        }
        if (wr == 0) {
#pragma unroll
            for (int mt = 4; mt < 8; ++mt) {
                fa[mt][0] = *(const bf16x8*)(Lb + aBase + mt * 1024);
                fa[mt][1] = *(const bf16x8*)(Lb + (aBase ^ 32) + mt * 1024);
            }
        }
        if (j < 15) { gld16(pB0 + 131072 + k1, Sn + 24576 + lc0);     // B1 of j+1
                      gld16(pB1 + 131072 + k1, Sn + 24576 + lc1); }
        PHASE_MFMA(0, 0);

        // ---------- phase 1: quadrant (0,1) ----------
        // reads: fb[2..3]; fa[4..7] for wr==1 (A1 overwritten only at p2).
        if (wr == 1) {
#pragma unroll
            for (int mt = 4; mt < 8; ++mt) {
                fa[mt][0] = *(const bf16x8*)(Lb + aBase + mt * 1024);
                fa[mt][1] = *(const bf16x8*)(Lb + (aBase ^ 32) + mt * 1024);
            }
        }
#pragma unroll
        for (int nt = 2; nt < 4; ++nt) {
            fb[nt][0] = *(const bf16x8*)(Lb + bBase + nt * 1024);
            fb[nt][1] = *(const bf16x8*)(Lb + (bBase ^ 32) + nt * 1024);
        }
        if (j < 14) { gld16(pA0 + k2, Sc + lc0);                      // A0 of j+2
                      gld16(pA1 + k2, Sc + lc1); }
        PHASE_MFMA(0, 1);

        // ---------- phase 2: quadrant (1,1) ----------
        if (j < 14) { gld16(pA0 + 131072 + k2, Sc + 8192 + lc0);      // A1 of j+2
                      gld16(pA1 + 131072 + k2, Sc + 8192 + lc1); }
        PHASE_MFMA(1, 1);

        // ---------- phase 3: quadrant (1,0) + checkpoint ----------
        if (j < 14) { gld16(pB0 + k2, Sc + 16384 + lc0);              // B0 of j+2
                      gld16(pB1 + k2, Sc + 16384 + lc1); }
        if (j < 14)       asm volatile("s_waitcnt vmcnt(6)" ::: "memory");
        else if (j == 14) asm volatile("s_waitcnt vmcnt(0)" ::: "memory");
        PHASE_MFMA(1, 0);
    }

    // ---- epilogue: C/D layout col=lane&15, row=quad*4+reg (R2-verified) ----
    const int orow0 = bm + wr * 128 + quad * 4;
    const int ocol0 = bn + wc * 64 + r16;
#pragma unroll
    for (int nt = 0; nt < 4; ++nt) {
        const float bv = bias[ocol0 + nt * 16];
#pragma unroll
        for (int mt = 0; mt < 8; ++mt) {
            float* orow = out + (size_t)(orow0 + mt * 16) * 1024 + (ocol0 + nt * 16);
#pragma unroll
            for (int i = 0; i < 4; ++i)
                orow[(size_t)i * 1024] = acc[mt][nt][i] + bv;
        }
    }
}

// ---------------- fallback gemm (ws too small): old 128x128, fp32 A ----------------
template <bool XF32>
__global__ __launch_bounds__(256) void gemm_bt(
    const void* __restrict__ X_, const unsigned short* __restrict__ Wt,
    const float* __restrict__ bias, float* __restrict__ out)
{
    __shared__ __align__(16) unsigned short lA[128 * 32];
    __shared__ __align__(16) unsigned short lB[128 * 32];

    const int t    = threadIdx.x;
    const int lane = t & 63;
    const int w    = t >> 6;
    const int bm   = blockIdx.x * 128;
    const int bn   = blockIdx.y * 128;
    const int wm   = (w & 1) * 64;
    const int wn   = (w >> 1) * 64;
    const int r16  = lane & 15;
    const int quad = lane >> 4;

    const int srow = t >> 2;
    const int gc   = (t & 3) ^ ((srow >> 1) & 3);
    unsigned short* lsA = lA + t * 8;
    unsigned short* lsB = lB + t * 8;
    const size_t ga0 = (size_t)(bm + srow) * 1024 + gc * 8;
    const size_t ga1 = (size_t)(bm + srow + 64) * 1024 + gc * 8;
    const unsigned short* gB0 = Wt + (size_t)(bn + srow) * 1024 + gc * 8;

    const int p    = (quad ^ ((r16 >> 1) & 3)) * 8;
    const int aoff = (wm + r16) * 32 + p;
    const int boff = (wn + r16) * 32 + p;

    const unsigned short* Xb = (const unsigned short*)X_;
    const float*          Xf = (const float*)X_;

    f32x4 acc[4][4];
#pragma unroll
    for (int i = 0; i < 4; ++i)
#pragma unroll
        for (int j = 0; j < 4; ++j) {
            f32x4 z = {0.f, 0.f, 0.f, 0.f};
            acc[i][j] = z;
        }

    for (int kt = 0; kt < 1024; kt += 32) {
        if (XF32) {
            f32x4 a0 = *(const f32x4*)(Xf + ga0 + kt);
            f32x4 a1 = *(const f32x4*)(Xf + ga0 + kt + 4);
            f32x4 a2 = *(const f32x4*)(Xf + ga1 + kt);
            f32x4 a3 = *(const f32x4*)(Xf + ga1 + kt + 4);
            *(ushort8*)lsA          = cvt8(a0, a1);
            *(ushort8*)(lsA + 2048) = cvt8(a2, a3);
        } else {
            gld16(Xb + ga0 + kt, lsA);
            gld16(Xb + ga1 + kt, lsA + 2048);
        }
        gld16(gB0 + kt,             lsB);
        gld16(gB0 + kt + 64 * 1024, lsB + 2048);
        __syncthreads();

        bf16x8 fa[4], fb[4];
#pragma unroll
        for (int mt = 0; mt < 4; ++mt) fa[mt] = *(const bf16x8*)(lA + aoff + mt * 16 * 32);
#pragma unroll
        for (int nt = 0; nt < 4; ++nt) fb[nt] = *(const bf16x8*)(lB + boff + nt * 16 * 32);

#pragma unroll
        for (int mt = 0; mt < 4; ++mt)
#pragma unroll
            for (int nt = 0; nt < 4; ++nt)
                acc[mt][nt] = __builtin_amdgcn_mfma_f32_16x16x32_bf16(
                    fa[mt], fb[nt], acc[mt][nt], 0, 0, 0);

        __syncthreads();
    }

    const int orow0 = bm + wm + quad * 4;
    const int ocol0 = bn + wn + r16;
#pragma unroll
    for (int nt = 0; nt < 4; ++nt) {
        const float bv = bias[ocol0 + nt * 16];
#pragma unroll
        for (int mt = 0; mt < 4; ++mt)
#pragma unroll
            for (int i = 0; i < 4; ++i)
                out[(size_t)(orow0 + mt * 16 + i) * 1024 + (ocol0 + nt * 16)] =
                    acc[mt][nt][i] + bv;
    }
}

extern "C" void kernel_launch(void* const* d_in, const int* in_sizes, int n_in,
                              void* d_out, int out_size, void* d_ws, size_t ws_size,
                              hipStream_t stream) {
    const float* x  = (const float*)d_in[0];   // [M][1024]
    const float* W  = (const float*)d_in[1];   // [1024][1024]
    const float* b  = (const float*)d_in[2];   // [1024]
    const float* A  = (const float*)d_in[3];   // [16][1024]
    const float* Bm = (const float*)d_in[4];   // [1024][16]
    float* out = (float*)d_out;

    const int M = in_sizes[0] / 1024;          // 16384

    const bool fast = (ws_size >= ((size_t)(M)*1024*2 + (2u << 20) + 4096)) &&
                      (M % 256 == 0);
    if (fast) {
        unsigned short* xbf  = (unsigned short*)d_ws;
        unsigned short* Weff = xbf + (size_t)M * 1024;
        hipLaunchKernelGGL(prep, dim3(512 + M / 2), dim3(256), 0, stream,
                           x, W, A, Bm, xbf, Weff);
        hipLaunchKernelGGL(gemm256, dim3((M / 256) * 4), dim3(512), 131072, stream,
                           xbf, Weff, b, out);
    } else {
        unsigned short* Weff = (unsigned short*)d_ws;
        hipLaunchKernelGGL(prep, dim3(512), dim3(256), 0, stream,
                           x, W, A, Bm, (unsigned short*)nullptr, Weff);
        hipLaunchKernelGGL((gemm_bt<true>), dim3(M / 128, 8), dim3(256), 0, stream,
                           (const void*)x, Weff, b, out);
    }
}

// Round 2
// 151.895 us; speedup vs baseline: 1.1516x; 1.1516x over previous
//
#include <hip/hip_runtime.h>

// LoRA linear, fp32 in/out: out = x @ (W + 2*B@A)^T + b
//   prep:   [0..511] Weff = bf16(W + 2*B@A) (2 MiB); [512..] xbf = bf16(x) (32 MiB)
//   gemm256: 256x256x64 8-phase-schedule bf16 MFMA GEMM (HK/m201 template, plain HIP):
//            STRIDED wave->frag mapping (R2 fix: even 12/4/8/0 ds_reads per phase),
//            counted vmcnt(6) (never drain-0 in loop), raw s_barrier, XOR k-chunk
//            swizzle (2-way max), setprio around MFMA clusters, XCD-chunked blockIdx.
//   Fallback (ws too small): old 128x128 kernel, A staged via fp32 loads + HW cvt.

typedef __bf16 bf16x8 __attribute__((ext_vector_type(8)));
typedef float f32x4 __attribute__((ext_vector_type(4)));
typedef unsigned short ushort8 __attribute__((ext_vector_type(8)));

__device__ __forceinline__ unsigned short f2bf(float f) {
    __bf16 h = (__bf16)f;                       // HW RNE convert
    union { __bf16 b; unsigned short u; } v; v.b = h; return v.u;
}
__device__ __forceinline__ ushort8 cvt8(f32x4 a, f32x4 b) {
    ushort8 o;
#pragma unroll
    for (int i = 0; i < 4; ++i) { o[i] = f2bf(a[i]); o[i + 4] = f2bf(b[i]); }
    return o;
}
__device__ __forceinline__ void gld16(const unsigned short* g, unsigned short* l) {
    __builtin_amdgcn_global_load_lds(
        (const __attribute__((address_space(1))) unsigned int*)g,
        (__attribute__((address_space(3))) unsigned int*)l, 16, 0, 0);
}

#define FENCE() asm volatile("" ::: "memory")
#define BARRIER() do { FENCE(); __builtin_amdgcn_s_barrier(); FENCE(); } while (0)

// ---------------- prep: Weff fold + x conversion (unchanged) ----------------
__global__ __launch_bounds__(256) void prep(
    const float* __restrict__ X, const float* __restrict__ W,
    const float* __restrict__ A, const float* __restrict__ B,
    unsigned short* __restrict__ xbf, unsigned short* __restrict__ Weff)
{
    const int b = blockIdx.x;
    if (b < 512) {
        const int idx = b * 256 + threadIdx.x;
        const int o  = idx >> 7;
        const int kc = (idx & 127) << 3;
        float br[16];
#pragma unroll
        for (int r = 0; r < 16; ++r) br[r] = 2.0f * B[o * 16 + r];
        float acc[8];
        const float* wrow = W + (size_t)o * 1024 + kc;
#pragma unroll
        for (int j = 0; j < 8; ++j) acc[j] = wrow[j];
#pragma unroll
        for (int r = 0; r < 16; ++r) {
            const float* arow = A + r * 1024 + kc;
#pragma unroll
            for (int j = 0; j < 8; ++j) acc[j] += br[r] * arow[j];
        }
        ushort8 o8;
#pragma unroll
        for (int j = 0; j < 8; ++j) o8[j] = f2bf(acc[j]);
        *(ushort8*)(Weff + (size_t)o * 1024 + kc) = o8;
    } else {
        const size_t i = ((size_t)(b - 512) * 256 + threadIdx.x) * 8;
        f32x4 a = *(const f32x4*)(X + i);
        f32x4 c = *(const f32x4*)(X + i + 4);
        *(ushort8*)(xbf + i) = cvt8(a, c);
    }
}

// ---------------- gemm256: 8-phase 256x256 schedule ----------------
// Geometry: BM=BN=256, BK=64, 512 thr = 8 waves (2M x 4N).
// STRIDED frag mapping: wave (wr,wc) owns m-frags (2*mt+wr)*16 (mt=0..7; mt<4 in
//   A0-half, mt>=4 in A1-half) and n-frags (wc+4*nt)*16 (nt=0..3; nt<2 in B0,
//   nt>=2 in B1). => per-phase reads: p0: fa[0..3]+fb[0..1] (12), p1: fb[2..3]
//   (4), p2: fa[4..7] (8), p3: 0 (fb[0..1] reused from regs).
// LDS 128 KiB: 2 bufs x {A0:0, A1:8192, B0:16384, B1:24576} ushorts (16 KiB each,
//   [128 rows][64] bf16). half-tile = 512 thr x 2 gld16.
// Swizzle: 16B-chunk c of row r stored at chunk pos c^(r&7); global source
//   pre-swizzled, LDS dest linear (global_load_lds constraint, rule #21).
// Stage slots (tile j): p0 -> B1(j+1) into NEXT buf; p1 -> A0(j+2), p2 -> B0(j+2),
//   p3 -> A1(j+2) into CUR buf (each region's last read is >=1 barrier earlier).
// vmcnt: checkpoint once per tile at p3. Queue there (14): [A0,B0,A1](j+1) from
//   tile j-1 + [B1(j+1), A0,B0,A1(j+2)] from tile j. vmcnt(6) retires the oldest
//   8 = all of tile j+1. j=14: vmcnt(0); j>=14: no staging beyond tile 15.
template<int MH, int NH>
__device__ __forceinline__ void qmfma(f32x4 (&acc)[8][4],
                                      const bf16x8 (&fa)[8][2],
                                      const bf16x8 (&fb)[4][2]) {
#pragma unroll
    for (int m2 = 0; m2 < 4; ++m2)
#pragma unroll
        for (int n2 = 0; n2 < 2; ++n2)
#pragma unroll
            for (int ks = 0; ks < 2; ++ks)
                acc[MH * 4 + m2][NH * 2 + n2] = __builtin_amdgcn_mfma_f32_16x16x32_bf16(
                    fa[MH * 4 + m2][ks], fb[NH * 2 + n2][ks],
                    acc[MH * 4 + m2][NH * 2 + n2], 0, 0, 0);
}

#define PHASE_MFMA(MH, NH)                                          \
    do { BARRIER();                                                 \
         asm volatile("s_waitcnt lgkmcnt(0)" ::: "memory");         \
         __builtin_amdgcn_sched_barrier(0); /* rule 18 */           \
         __builtin_amdgcn_s_setprio(1);                             \
         qmfma<MH, NH>(acc, fa, fb);                                \
         __builtin_amdgcn_s_setprio(0);                             \
         BARRIER(); } while (0)

__global__ __launch_bounds__(512, 2) void gemm256(
    const unsigned short* __restrict__ Xb,     // bf16 [M][1024]
    const unsigned short* __restrict__ Wt,     // bf16 Weff [1024][1024]
    const float* __restrict__ bias,            // fp32 [1024]
    float* __restrict__ out)                   // fp32 [M][1024]
{
    extern __shared__ __align__(16) unsigned short lds[];   // 131072 B

    const int t    = threadIdx.x;
    const int lane = t & 63;
    const int w    = t >> 6;
    const int wr   = w >> 2;        // 0..1 (M)
    const int wc   = w & 3;         // 0..3 (N)
    const int r16  = lane & 15;
    const int quad = lane >> 4;

    // XCD-chunked block swizzle (nwg=256 % 8 == 0 -> bijective). N/BN=4 fixed.
    const int nwg = gridDim.x;
    int swz = blockIdx.x;
    if ((nwg & 7) == 0) swz = (swz & 7) * (nwg >> 3) + (swz >> 3);
    const int bm = (swz >> 2) * 256;
    const int bn = (swz & 3) * 256;

    // ---- staging constants: thread t owns chunks c0,c1 of each half-tile ----
    const int c0 = w * 128 + lane, c1 = c0 + 64;       // chunk ids (16 B each)
    const int r0 = c0 >> 3,        r1 = c1 >> 3;       // half-local rows 0..127
    const int s0c = (c0 & 7) ^ (r0 & 7);               // pre-swizzled src chunk
    const int s1c = (c1 & 7) ^ (r1 & 7);
    const unsigned short* pA0 = Xb + (size_t)(bm + r0) * 1024 + s0c * 8;
    const unsigned short* pA1 = Xb + (size_t)(bm + r1) * 1024 + s1c * 8;
    const unsigned short* pB0 = Wt + (size_t)(bn + r0) * 1024 + s0c * 8;
    const unsigned short* pB1 = Wt + (size_t)(bn + r1) * 1024 + s1c * 8;
    const int lc0 = c0 * 8, lc1 = c1 * 8;              // linear LDS dest (ushorts)

    // ---- reader constants (strided mapping) ----
    // fa[mt]: addr = (mt>>2)*8192 + (mt&3)*2048 + aB;  fb[nt]: (nt>>1)*8192 +
    // (nt&1)*4096 + bB.  ^32 toggles the k-subtile (ks).
    const int sw  = (quad ^ (r16 & 7)) * 8;            // swizzled chunk offset
    const int aB  = wr * 1024 + r16 * 64 + sw;
    const int bB  = 16384 + wc * 1024 + r16 * 64 + sw;

    f32x4 acc[8][4];
#pragma unroll
    for (int i = 0; i < 8; ++i)
#pragma unroll
        for (int jj = 0; jj < 4; ++jj)
            acc[i][jj] = (f32x4){0.f, 0.f, 0.f, 0.f};

    // ---- prologue: tile0 (A0,B0,A1,B1) -> buf0; tile1 (A0,B0,A1) -> buf1 ----
    // FENCE between groups pins issue order so vmcnt counting is exact.
    gld16(pA0,               lds + lc0);            gld16(pA1,               lds + lc1);            FENCE();
    gld16(pB0,               lds + 16384 + lc0);    gld16(pB1,               lds + 16384 + lc1);    FENCE();
    gld16(pA0 + 131072,      lds + 8192  + lc0);    gld16(pA1 + 131072,      lds + 8192  + lc1);    FENCE();
    gld16(pB0 + 131072,      lds + 24576 + lc0);    gld16(pB1 + 131072,      lds + 24576 + lc1);    FENCE();
    gld16(pA0 + 64,          lds + 32768 + lc0);    gld16(pA1 + 64,          lds + 32768 + lc1);    FENCE();
    gld16(pB0 + 64,          lds + 49152 + lc0);    gld16(pB1 + 64,          lds + 49152 + lc1);    FENCE();
    gld16(pA0 + 131072 + 64, lds + 40960 + lc0);    gld16(pA1 + 131072 + 64, lds + 40960 + lc1);
    asm volatile("s_waitcnt vmcnt(6)" ::: "memory");   // tile0 fully landed
    BARRIER();

#pragma unroll 2
    for (int j = 0; j < 16; ++j) {
        const unsigned short* Lb = lds + (j & 1) * 32768;        // compute buf
        unsigned short* Sc = lds + (j & 1) * 32768;              // stage p1..p3
        unsigned short* Sn = lds + ((j & 1) ^ 1) * 32768;        // stage p0
        const int k1 = (j + 1) * 64, k2 = (j + 2) * 64;

        bf16x8 fa[8][2], fb[4][2];

        // ---------- phase 0: quadrant (0,0) — reads fa[0..3], fb[0..1] ----------
#pragma unroll
        for (int mt = 0; mt < 4; ++mt) {
            fa[mt][0] = *(const bf16x8*)(Lb + aB + mt * 2048);
            fa[mt][1] = *(const bf16x8*)(Lb + ((aB + mt * 2048) ^ 32));
        }
#pragma unroll
        for (int nt = 0; nt < 2; ++nt) {
            fb[nt][0] = *(const bf16x8*)(Lb + bB + nt * 4096);
            fb[nt][1] = *(const bf16x8*)(Lb + ((bB + nt * 4096) ^ 32));
        }
        if (j < 15) { gld16(pB0 + 131072 + k1, Sn + 24576 + lc0);     // B1(j+1) -> next
                      gld16(pB1 + 131072 + k1, Sn + 24576 + lc1); }
        asm volatile("s_waitcnt lgkmcnt(8)" ::: "memory");  // 12-read phase pacing
        PHASE_MFMA(0, 0);

        // ---------- phase 1: quadrant (0,1) — reads fb[2..3] ----------
#pragma unroll
        for (int nt = 2; nt < 4; ++nt) {
            fb[nt][0] = *(const bf16x8*)(Lb + bB + 8192 + (nt - 2) * 4096);
            fb[nt][1] = *(const bf16x8*)(Lb + ((bB + 8192 + (nt - 2) * 4096) ^ 32));
        }
        if (j < 14) { gld16(pA0 + k2, Sc + lc0);                      // A0(j+2) -> cur
                      gld16(pA1 + k2, Sc + lc1); }
        PHASE_MFMA(0, 1);

        // ---------- phase 2: quadrant (1,1) — reads fa[4..7] ----------
#pragma unroll
        for (int mt = 4; mt < 8; ++mt) {
            fa[mt][0] = *(const bf16x8*)(Lb + aB + 8192 + (mt - 4) * 2048);
            fa[mt][1] = *(const bf16x8*)(Lb + ((aB + 8192 + (mt - 4) * 2048) ^ 32));
        }
        if (j < 14) { gld16(pB0 + k2, Sc + 16384 + lc0);              // B0(j+2) -> cur
                      gld16(pB1 + k2, Sc + 16384 + lc1); }
        PHASE_MFMA(1, 1);

        // ---------- phase 3: quadrant (1,0) — no reads + checkpoint ----------
        if (j < 14) { gld16(pA0 + 131072 + k2, Sc + 8192 + lc0);      // A1(j+2) -> cur
                      gld16(pA1 + 131072 + k2, Sc + 8192 + lc1); }
        if (j < 14)       asm volatile("s_waitcnt vmcnt(6)" ::: "memory");
        else if (j == 14) asm volatile("s_waitcnt vmcnt(0)" ::: "memory");
        PHASE_MFMA(1, 0);
    }

    // ---- epilogue: frag (mt,nt) -> rows bm+(2mt+wr)*16+quad*4, cols bn+(wc+4nt)*16+r16 ----
    const int orow0 = bm + wr * 16 + quad * 4;
    const int ocol0 = bn + wc * 16 + r16;
#pragma unroll
    for (int nt = 0; nt < 4; ++nt) {
        const float bv = bias[ocol0 + nt * 64];
#pragma unroll
        for (int mt = 0; mt < 8; ++mt) {
            float* orow = out + (size_t)(orow0 + mt * 32) * 1024 + (ocol0 + nt * 64);
#pragma unroll
            for (int i = 0; i < 4; ++i)
                orow[(size_t)i * 1024] = acc[mt][nt][i] + bv;
        }
    }
}

// ---------------- fallback gemm (ws too small): old 128x128, fp32 A ----------------
template <bool XF32>
__global__ __launch_bounds__(256) void gemm_bt(
    const void* __restrict__ X_, const unsigned short* __restrict__ Wt,
    const float* __restrict__ bias, float* __restrict__ out)
{
    __shared__ __align__(16) unsigned short lA[128 * 32];
    __shared__ __align__(16) unsigned short lB[128 * 32];

    const int t    = threadIdx.x;
    const int lane = t & 63;
    const int w    = t >> 6;
    const int bm   = blockIdx.x * 128;
    const int bn   = blockIdx.y * 128;
    const int wm   = (w & 1) * 64;
    const int wn   = (w >> 1) * 64;
    const int r16  = lane & 15;
    const int quad = lane >> 4;

    const int srow = t >> 2;
    const int gc   = (t & 3) ^ ((srow >> 1) & 3);
    unsigned short* lsA = lA + t * 8;
    unsigned short* lsB = lB + t * 8;
    const size_t ga0 = (size_t)(bm + srow) * 1024 + gc * 8;
    const size_t ga1 = (size_t)(bm + srow + 64) * 1024 + gc * 8;
    const unsigned short* gB0 = Wt + (size_t)(bn + srow) * 1024 + gc * 8;

    const int p    = (quad ^ ((r16 >> 1) & 3)) * 8;
    const int aoff = (wm + r16) * 32 + p;
    const int boff = (wn + r16) * 32 + p;

    const unsigned short* Xb = (const unsigned short*)X_;
    const float*          Xf = (const float*)X_;

    f32x4 acc[4][4];
#pragma unroll
    for (int i = 0; i < 4; ++i)
#pragma unroll
        for (int j = 0; j < 4; ++j) {
            f32x4 z = {0.f, 0.f, 0.f, 0.f};
            acc[i][j] = z;
        }

    for (int kt = 0; kt < 1024; kt += 32) {
        if (XF32) {
            f32x4 a0 = *(const f32x4*)(Xf + ga0 + kt);
            f32x4 a1 = *(const f32x4*)(Xf + ga0 + kt + 4);
            f32x4 a2 = *(const f32x4*)(Xf + ga1 + kt);
            f32x4 a3 = *(const f32x4*)(Xf + ga1 + kt + 4);
            *(ushort8*)lsA          = cvt8(a0, a1);
            *(ushort8*)(lsA + 2048) = cvt8(a2, a3);
        } else {
            gld16(Xb + ga0 + kt, lsA);
            gld16(Xb + ga1 + kt, lsA + 2048);
        }
        gld16(gB0 + kt,             lsB);
        gld16(gB0 + kt + 64 * 1024, lsB + 2048);
        __syncthreads();

        bf16x8 fa[4], fb[4];
#pragma unroll
        for (int mt = 0; mt < 4; ++mt) fa[mt] = *(const bf16x8*)(lA + aoff + mt * 16 * 32);
#pragma unroll
        for (int nt = 0; nt < 4; ++nt) fb[nt] = *(const bf16x8*)(lB + boff + nt * 16 * 32);

#pragma unroll
        for (int mt = 0; mt < 4; ++mt)
#pragma unroll
            for (int nt = 0; nt < 4; ++nt)
                acc[mt][nt] = __builtin_amdgcn_mfma_f32_16x16x32_bf16(
                    fa[mt], fb[nt], acc[mt][nt], 0, 0, 0);

        __syncthreads();
    }

    const int orow0 = bm + wm + quad * 4;
    const int ocol0 = bn + wn + r16;
#pragma unroll
    for (int nt = 0; nt < 4; ++nt) {
        const float bv = bias[ocol0 + nt * 16];
#pragma unroll
        for (int mt = 0; mt < 4; ++mt)
#pragma unroll
            for (int i = 0; i < 4; ++i)
                out[(size_t)(orow0 + mt * 16 + i) * 1024 + (ocol0 + nt * 16)] =
                    acc[mt][nt][i] + bv;
    }
}

extern "C" void kernel_launch(void* const* d_in, const int* in_sizes, int n_in,
                              void* d_out, int out_size, void* d_ws, size_t ws_size,
                              hipStream_t stream) {
    const float* x  = (const float*)d_in[0];   // [M][1024]
    const float* W  = (const float*)d_in[1];   // [1024][1024]
    const float* b  = (const float*)d_in[2];   // [1024]
    const float* A  = (const float*)d_in[3];   // [16][1024]
    const float* Bm = (const float*)d_in[4];   // [1024][16]
    float* out = (float*)d_out;

    const int M = in_sizes[0] / 1024;          // 16384

    const bool fast = (ws_size >= ((size_t)(M)*1024*2 + (2u << 20) + 4096)) &&
                      (M % 256 == 0);
    if (fast) {
        unsigned short* xbf  = (unsigned short*)d_ws;
        unsigned short* Weff = xbf + (size_t)M * 1024;
        hipLaunchKernelGGL(prep, dim3(512 + M / 2), dim3(256), 0, stream,
                           x, W, A, Bm, xbf, Weff);
        hipLaunchKernelGGL(gemm256, dim3((M / 256) * 4), dim3(512), 131072, stream,
                           xbf, Weff, b, out);
    } else {
        unsigned short* Weff = (unsigned short*)d_ws;
        hipLaunchKernelGGL(prep, dim3(512), dim3(256), 0, stream,
                           x, W, A, Bm, (unsigned short*)nullptr, Weff);
        hipLaunchKernelGGL((gemm_bt<true>), dim3(M / 128, 8), dim3(256), 0, stream,
                           (const void*)x, Weff, b, out);
    }
}